// Round 3
// baseline (907.394 us; speedup 1.0000x reference)
//
#include <hip/hip_runtime.h>

#define T_TOK 16384
#define HDIM  4096
#define NEXP  64
#define TAU   1e-4f

// ---------------------------------------------------------------------------
// Zero the repair counter (ws is poisoned 0xAA and never re-poisoned).
// ---------------------------------------------------------------------------
__global__ void zero_counter(int* counter) {
    if (threadIdx.x == 0) counter[0] = 0;
}

// ---------------------------------------------------------------------------
// Kernel A: fp32 logits, K-split partials.
// Block = 256 thr = 4 waves, tile = 64 tokens. Wave w owns experts [16w,16w+16).
// Lane = token. X staged in LDS (float4 units, XOR-(row&7) swizzle; read is one
// ds_read_b128 per k-quad). W read via wave-uniform addresses (readfirstlane
// base -> scalar loads / broadcast L1 hits; 16KB W-chunk is L1-resident).
// ---------------------------------------------------------------------------
__global__ __launch_bounds__(256, 4)
void gate_gemm_f32(const float* __restrict__ x, const float* __restrict__ w,
                   float* __restrict__ partial, int ksplit) {
    const int b      = blockIdx.x;
    const int kslice = b % ksplit;
    const int tblk   = b / ksplit;
    const int kspan  = HDIM / ksplit;
    const int k0     = kslice * kspan;

    __shared__ float Xs[64 * 64];

    const int tid  = threadIdx.x;
    const int lane = tid & 63;
    const int we0  = __builtin_amdgcn_readfirstlane((tid >> 6) << 4);

    float acc[16];
#pragma unroll
    for (int e = 0; e < 16; ++e) acc[e] = 0.f;

    for (int kc = k0; kc < k0 + kspan; kc += 64) {
        __syncthreads();
#pragma unroll
        for (int i = 0; i < 4; ++i) {
            const int L   = tid + 256 * i;     // 0..1023
            const int row = L >> 4;            // token row 0..63
            const int k4  = L & 15;            // float4 index 0..15
            const float4 v =
                *(const float4*)(x + (size_t)(tblk * 64 + row) * HDIM + kc + 4 * k4);
            *(float4*)(Xs + 4 * (row * 16 + (k4 ^ (row & 7)))) = v;
        }
        __syncthreads();
#pragma unroll
        for (int kq = 0; kq < 16; ++kq) {
            const float4 xv = *(const float4*)(Xs + 4 * (lane * 16 + (kq ^ (lane & 7))));
#pragma unroll
            for (int e = 0; e < 16; ++e) {
                const float4 wv =
                    *(const float4*)(w + (size_t)(we0 + e) * HDIM + (kc + 4 * kq));
                acc[e] += xv.x * wv.x + xv.y * wv.y + xv.z * wv.z + xv.w * wv.w;
            }
        }
    }

    const int t = tblk * 64 + lane;
    float* outp = partial + (size_t)kslice * T_TOK * NEXP + (size_t)t * NEXP + we0;
#pragma unroll
    for (int e = 0; e < 16; ++e) outp[e] = acc[e];
}

// ---------------------------------------------------------------------------
// Kernel B: sum K-split partials, fp32 top-17 per token (wave/token), flag
// tokens whose adjacent gap among ranks 0..16 is < TAU, write provisional out.
// Outputs (all float32, concatenated): ew(T,8) | ei(T,8) | ci(T,8) | ia(T,8).
// ---------------------------------------------------------------------------
__global__ __launch_bounds__(256)
void gate_topk_f32(const float* __restrict__ partial, int ksplit,
                   float* __restrict__ out, int* __restrict__ list,
                   int* __restrict__ counter) {
    const int wave = threadIdx.x >> 6;
    const int lane = threadIdx.x & 63;
    const int t = blockIdx.x * 4 + wave;

    float l = 0.f;
    for (int s = 0; s < ksplit; ++s)
        l += partial[(size_t)s * T_TOK * NEXP + (size_t)t * NEXP + lane];

    float v = l;
    const int idx = lane;
    float myval = -3.4e38f;
    int   myidx = 0;
#pragma unroll
    for (int r = 0; r < 17; ++r) {
        float bv = v;
        int   bi = idx;
#pragma unroll
        for (int s = 1; s < 64; s <<= 1) {
            const float ov = __shfl_xor(bv, s);
            const int   oi = __shfl_xor(bi, s);
            if (ov > bv || (ov == bv && oi < bi)) { bv = ov; bi = oi; }
        }
        if (lane == r) { myval = bv; myidx = bi; }
        if (idx == bi) v = -3.4e38f;
    }

    // ambiguity: any boundary (r,r+1), r=0..15, closer than TAU
    const float nxt = __shfl(myval, (lane + 1) & 63);
    const bool close = (lane < 16) && (myval - nxt < TAU);
    if (__ballot(close) != 0ull) {
        if (lane == 0) { const int p = atomicAdd(counter, 1); list[p] = t; }
    }

    const float m = __shfl(myval, 0);
    const float p = (lane < 16) ? expf(myval - m) : 0.f;
    float s8 = (lane < 8) ? p : 0.f;
#pragma unroll
    for (int s = 1; s < 64; s <<= 1) s8 += __shfl_xor(s8, s);

    float* ew = out;
    float* ei = out + (size_t)T_TOK * 8;
    float* ci = out + (size_t)2 * T_TOK * 8;
    float* ia = out + (size_t)3 * T_TOK * 8;
    if (lane < 8) {
        ew[(size_t)t * 8 + lane] = p / s8;
        ei[(size_t)t * 8 + lane] = (float)myidx;
        ia[(size_t)t * 8 + lane] = (float)myidx;
    } else if (lane < 16) {
        ci[(size_t)t * 8 + (lane - 8)] = (float)myidx;
    }
}

// ---------------------------------------------------------------------------
// Kernel C: fp64 repair of flagged tokens. One wave per token, lane = expert.
// Recomputes all 64 logits in fp64, redoes top-16, overwrites the token's
// outputs. Idempotent & order-independent -> deterministic despite atomics.
// ---------------------------------------------------------------------------
__global__ __launch_bounds__(256)
void gate_repair_f64(const float* __restrict__ x, const float* __restrict__ w,
                     const int* __restrict__ list, const int* __restrict__ counter,
                     float* __restrict__ out) {
    const int lane = threadIdx.x & 63;
    const int wid  = (int)((blockIdx.x * blockDim.x + threadIdx.x) >> 6);
    const int nw   = (int)((gridDim.x * blockDim.x) >> 6);
    const int n    = counter[0];

    for (int i = wid; i < n; i += nw) {
        const int t = __builtin_amdgcn_readfirstlane(list[i]);
        const float* xr = x + (size_t)t * HDIM;
        const float* wr = w + (size_t)lane * HDIM;
        double acc = 0.0;
        for (int k = 0; k < HDIM; k += 4) {
            const float4 xv = *(const float4*)(xr + k);
            const float4 wv = *(const float4*)(wr + k);
            acc = fma((double)xv.x, (double)wv.x, acc);
            acc = fma((double)xv.y, (double)wv.y, acc);
            acc = fma((double)xv.z, (double)wv.z, acc);
            acc = fma((double)xv.w, (double)wv.w, acc);
        }

        double v = acc;
        const int idx = lane;
        double mylog = -1.0e308;
        int    myidx = 0;
#pragma unroll
        for (int r = 0; r < 16; ++r) {
            double bv = v;
            int    bi = idx;
#pragma unroll
            for (int s = 1; s < 64; s <<= 1) {
                const double ov = __shfl_xor(bv, s);
                const int    oi = __shfl_xor(bi, s);
                if (ov > bv || (ov == bv && oi < bi)) { bv = ov; bi = oi; }
            }
            if (lane == r) { mylog = bv; myidx = bi; }
            if (idx == bi) v = -1.0e308;
        }

        const double m = __shfl(mylog, 0);
        const float p = (lane < 16) ? expf((float)(mylog - m)) : 0.f;
        float s8 = (lane < 8) ? p : 0.f;
#pragma unroll
        for (int s = 1; s < 64; s <<= 1) s8 += __shfl_xor(s8, s);

        float* ew = out;
        float* ei = out + (size_t)T_TOK * 8;
        float* ci = out + (size_t)2 * T_TOK * 8;
        float* ia = out + (size_t)3 * T_TOK * 8;
        if (lane < 8) {
            ew[(size_t)t * 8 + lane] = p / s8;
            ei[(size_t)t * 8 + lane] = (float)myidx;
            ia[(size_t)t * 8 + lane] = (float)myidx;
        } else if (lane < 16) {
            ci[(size_t)t * 8 + (lane - 8)] = (float)myidx;
        }
    }
}

extern "C" void kernel_launch(void* const* d_in, const int* in_sizes, int n_in,
                              void* d_out, int out_size, void* d_ws, size_t ws_size,
                              hipStream_t stream) {
    const float* x = (const float*)d_in[0];
    const float* w = (const float*)d_in[1];
    float* out     = (float*)d_out;
    float* partial = (float*)d_ws;

    const size_t slice = (size_t)T_TOK * NEXP * sizeof(float);   // 4 MiB
    const size_t extra = (size_t)T_TOK * sizeof(int) + 64;       // list + counter
    int ksplit = 1;
    if      (ws_size >= 4 * slice + extra) ksplit = 4;
    else if (ws_size >= 2 * slice + extra) ksplit = 2;

    int* list    = (int*)((char*)d_ws + (size_t)ksplit * slice);
    int* counter = list + T_TOK;

    zero_counter<<<1, 64, 0, stream>>>(counter);
    gate_gemm_f32<<<ksplit * (T_TOK / 64), 256, 0, stream>>>(x, w, partial, ksplit);
    gate_topk_f32<<<T_TOK / 4, 256, 0, stream>>>(partial, ksplit, out, list, counter);
    gate_repair_f64<<<256, 256, 0, stream>>>(x, w, list, counter, out);
}

// Round 4
// 230.585 us; speedup vs baseline: 3.9352x; 3.9352x over previous
//
#include <hip/hip_runtime.h>

#define T_TOK 16384
#define HDIM  4096
#define NEXP  64
#define TAU   2e-4f

typedef unsigned short u16;
typedef u16   u16x8  __attribute__((ext_vector_type(8)));
typedef __bf16 bf16x8 __attribute__((ext_vector_type(8)));
typedef float f32x4  __attribute__((ext_vector_type(4)));

// round-to-nearest-even fp32 -> bf16 (as u16)
__device__ __forceinline__ u16 f2bf(float f) {
    unsigned u = __builtin_bit_cast(unsigned, f);
    unsigned r = u + 0x7FFFu + ((u >> 16) & 1u);
    return (u16)(r >> 16);
}
__device__ __forceinline__ float bf2f(u16 h) {
    unsigned u = ((unsigned)h) << 16;
    return __builtin_bit_cast(float, u);
}

__global__ void zero_counter(int* counter) {
    if (threadIdx.x == 0) counter[0] = 0;
}

// ---------------------------------------------------------------------------
// Pre-split W (fp32 64x4096) into bf16 hi/lo, stored in per-k-chunk MFMA
// fragment order so the GEMM's W staging is a linear 16B-unit copy.
// Chunk c (64 k) = 1024 units of 16B: [hi 512 | lo 512]; unit q = U ^ k8,
// U = (4*ks+nt)*64 + (e&15) + 16*g, k8 = 4*ks+g.  (A and B use the same
// (lane,j)->k packing, so any internal HW k-permutation cancels.)
// ---------------------------------------------------------------------------
__global__ __launch_bounds__(256)
void wsplit_kernel(const float* __restrict__ w, u16x8* __restrict__ wfrag) {
    const int id  = blockIdx.x * 256 + threadIdx.x;   // 0..32767
    const int e   = id >> 9;
    const int k8g = id & 511;
    const int k   = k8g * 8;

    const float* wp = w + (size_t)e * HDIM + k;
    const float4 v0 = *(const float4*)wp;
    const float4 v1 = *(const float4*)(wp + 4);
    const float fv[8] = {v0.x, v0.y, v0.z, v0.w, v1.x, v1.y, v1.z, v1.w};
    u16x8 hv, lv;
#pragma unroll
    for (int j = 0; j < 8; ++j) {
        const u16 h = f2bf(fv[j]);
        hv[j] = h;
        lv[j] = f2bf(fv[j] - bf2f(h));
    }
    const int chunk = k >> 6;
    const int k8 = (k >> 3) & 7, ks = k8 >> 2, g = k8 & 3, nt = e >> 4;
    const int U = ((((ks << 2) + nt) << 6) + (e & 15) + 16 * g);
    const int q = U ^ k8;
    wfrag[(size_t)chunk * 1024 + q]       = hv;
    wfrag[(size_t)chunk * 1024 + 512 + q] = lv;
}

// ---------------------------------------------------------------------------
// MFMA GEMM: logits[t][e] = sum_h x[t][h]*w[e][h] via bf16-split 3-product.
// Block = 256 thr = 4 waves; tile 64 tokens x 64 experts; K-chunk 64.
// LDS (32 KiB, 16B units): [W hi 512 | W lo 512 | X hi 512 | X lo 512].
// X fragments: U = ks*256 + mt*64 + (t&15) + 16*g, phys = U ^ (4*ks+g).
// All ds reads/writes are per-lane-16B with distinct bank groups per 8 lanes.
// ---------------------------------------------------------------------------
__global__ __launch_bounds__(256, 3)
void gate_gemm_mfma(const float* __restrict__ x, const u16x8* __restrict__ wfrag,
                    float* __restrict__ partial, int ksplit) {
    const int b      = blockIdx.x;
    const int kslice = b % ksplit;
    const int tblk   = b / ksplit;
    const int kspan  = HDIM / ksplit;
    const int k0     = kslice * kspan;
    const int t0     = tblk * 64;

    __shared__ __align__(16) u16 smem[2048 * 8];   // 32 KiB

    const int tid  = threadIdx.x;
    const int lane = tid & 63;
    const int wv   = tid >> 6;          // wave = M-tile 0..3

    f32x4 acc[4];
#pragma unroll
    for (int nt = 0; nt < 4; ++nt) acc[nt] = (f32x4){0.f, 0.f, 0.f, 0.f};

    for (int kc = k0; kc < k0 + kspan; kc += 64) {
        const int chunkIdx = kc >> 6;
        __syncthreads();

        // ---- stage W: linear copy of 1024 16B units (global is pre-ordered)
        const u16x8* wsrc = wfrag + (size_t)chunkIdx * 1024;
#pragma unroll
        for (int i = 0; i < 4; ++i) {
            const int u = tid + 256 * i;
            *(u16x8*)(smem + (size_t)u * 8) = wsrc[u];
        }

        // ---- stage X: load 8 consecutive k fp32, split to bf16 hi/lo frags
#pragma unroll
        for (int i = 0; i < 2; ++i) {
            const int L   = tid + 256 * i;   // 0..511
            const int row = L >> 3;          // token row 0..63
            const int k8  = L & 7;
            const float* xp = x + (size_t)(t0 + row) * HDIM + kc + 8 * k8;
            const float4 v0 = *(const float4*)xp;
            const float4 v1 = *(const float4*)(xp + 4);
            const float fv[8] = {v0.x, v0.y, v0.z, v0.w, v1.x, v1.y, v1.z, v1.w};
            u16x8 hv, lv;
#pragma unroll
            for (int j = 0; j < 8; ++j) {
                const u16 h = f2bf(fv[j]);
                hv[j] = h;
                lv[j] = f2bf(fv[j] - bf2f(h));
            }
            const int g = k8 & 3, ks = k8 >> 2, mt = row >> 4;
            const int U = (((ks << 2) + mt) << 6) + (row & 15) + 16 * g;
            const int phys = U ^ k8;
            *(u16x8*)(smem + (size_t)(1024 + phys) * 8) = hv;
            *(u16x8*)(smem + (size_t)(1536 + phys) * 8) = lv;
        }
        __syncthreads();

        // ---- MFMA: 2 k-steps x 4 N-tiles x 3 products
#pragma unroll
        for (int ks = 0; ks < 2; ++ks) {
            const int xo = (ks << 2) + (lane >> 4);
            const int ux = ((((ks << 2) + wv) << 6) + lane) ^ xo;
            const bf16x8 axh = __builtin_bit_cast(bf16x8, *(const u16x8*)(smem + (size_t)(1024 + ux) * 8));
            const bf16x8 axl = __builtin_bit_cast(bf16x8, *(const u16x8*)(smem + (size_t)(1536 + ux) * 8));
#pragma unroll
            for (int nt = 0; nt < 4; ++nt) {
                const int uw = ((((ks << 2) + nt) << 6) + lane) ^ xo;
                const bf16x8 bh = __builtin_bit_cast(bf16x8, *(const u16x8*)(smem + (size_t)uw * 8));
                const bf16x8 bl = __builtin_bit_cast(bf16x8, *(const u16x8*)(smem + (size_t)(512 + uw) * 8));
                acc[nt] = __builtin_amdgcn_mfma_f32_16x16x32_bf16(axh, bh, acc[nt], 0, 0, 0);
                acc[nt] = __builtin_amdgcn_mfma_f32_16x16x32_bf16(axh, bl, acc[nt], 0, 0, 0);
                acc[nt] = __builtin_amdgcn_mfma_f32_16x16x32_bf16(axl, bh, acc[nt], 0, 0, 0);
            }
        }
    }

    // epilogue: D row = (lane>>4)*4 + r (token), col = lane&15 (expert within nt)
    float* op = partial + (size_t)kslice * T_TOK * NEXP;
    const int trow = t0 + wv * 16 + ((lane >> 4) << 2);
    const int ecol = lane & 15;
#pragma unroll
    for (int nt = 0; nt < 4; ++nt)
#pragma unroll
        for (int r = 0; r < 4; ++r)
            op[(size_t)(trow + r) * NEXP + nt * 16 + ecol] = acc[nt][r];
}

// ---------------------------------------------------------------------------
// Top-k: sum K-split partials, fp32 top-17/token, flag gap<TAU for repair.
// Outputs (float32): ew(T,8) | ei(T,8) | ci(T,8) | ia(T,8).
// ---------------------------------------------------------------------------
__global__ __launch_bounds__(256)
void gate_topk_f32(const float* __restrict__ partial, int ksplit,
                   float* __restrict__ out, int* __restrict__ list,
                   int* __restrict__ counter) {
    const int wave = threadIdx.x >> 6;
    const int lane = threadIdx.x & 63;
    const int t = blockIdx.x * 4 + wave;

    float l = 0.f;
    for (int s = 0; s < ksplit; ++s)
        l += partial[(size_t)s * T_TOK * NEXP + (size_t)t * NEXP + lane];

    float v = l;
    const int idx = lane;
    float myval = -3.4e38f;
    int   myidx = 0;
#pragma unroll
    for (int r = 0; r < 17; ++r) {
        float bv = v;
        int   bi = idx;
#pragma unroll
        for (int s = 1; s < 64; s <<= 1) {
            const float ov = __shfl_xor(bv, s);
            const int   oi = __shfl_xor(bi, s);
            if (ov > bv || (ov == bv && oi < bi)) { bv = ov; bi = oi; }
        }
        if (lane == r) { myval = bv; myidx = bi; }
        if (idx == bi) v = -3.4e38f;
    }

    const float nxt = __shfl(myval, (lane + 1) & 63);
    const bool close = (lane < 16) && (myval - nxt < TAU);
    if (__ballot(close) != 0ull) {
        if (lane == 0) { const int p = atomicAdd(counter, 1); list[p] = t; }
    }

    const float m = __shfl(myval, 0);
    const float p = (lane < 16) ? expf(myval - m) : 0.f;
    float s8 = (lane < 8) ? p : 0.f;
#pragma unroll
    for (int s = 1; s < 64; s <<= 1) s8 += __shfl_xor(s8, s);

    float* ew = out;
    float* ei = out + (size_t)T_TOK * 8;
    float* ci = out + (size_t)2 * T_TOK * 8;
    float* ia = out + (size_t)3 * T_TOK * 8;
    if (lane < 8) {
        ew[(size_t)t * 8 + lane] = p / s8;
        ei[(size_t)t * 8 + lane] = (float)myidx;
        ia[(size_t)t * 8 + lane] = (float)myidx;
    } else if (lane < 16) {
        ci[(size_t)t * 8 + (lane - 8)] = (float)myidx;
    }
}

// ---------------------------------------------------------------------------
// FP64 repair of flagged tokens (wave/token, lane=expert). Deterministic.
// ---------------------------------------------------------------------------
__global__ __launch_bounds__(256)
void gate_repair_f64(const float* __restrict__ x, const float* __restrict__ w,
                     const int* __restrict__ list, const int* __restrict__ counter,
                     float* __restrict__ out) {
    const int lane = threadIdx.x & 63;
    const int wid  = (int)((blockIdx.x * blockDim.x + threadIdx.x) >> 6);
    const int nw   = (int)((gridDim.x * blockDim.x) >> 6);
    const int n    = counter[0];

    for (int i = wid; i < n; i += nw) {
        const int t = __builtin_amdgcn_readfirstlane(list[i]);
        const float* xr = x + (size_t)t * HDIM;
        const float* wr = w + (size_t)lane * HDIM;
        double acc = 0.0;
        for (int k = 0; k < HDIM; k += 4) {
            const float4 xv = *(const float4*)(xr + k);
            const float4 wv = *(const float4*)(wr + k);
            acc = fma((double)xv.x, (double)wv.x, acc);
            acc = fma((double)xv.y, (double)wv.y, acc);
            acc = fma((double)xv.z, (double)wv.z, acc);
            acc = fma((double)xv.w, (double)wv.w, acc);
        }

        double v = acc;
        const int idx = lane;
        double mylog = -1.0e308;
        int    myidx = 0;
#pragma unroll
        for (int r = 0; r < 16; ++r) {
            double bv = v;
            int    bi = idx;
#pragma unroll
            for (int s = 1; s < 64; s <<= 1) {
                const double ov = __shfl_xor(bv, s);
                const int    oi = __shfl_xor(bi, s);
                if (ov > bv || (ov == bv && oi < bi)) { bv = ov; bi = oi; }
            }
            if (lane == r) { mylog = bv; myidx = bi; }
            if (idx == bi) v = -1.0e308;
        }

        const double m = __shfl(mylog, 0);
        const float p = (lane < 16) ? expf((float)(mylog - m)) : 0.f;
        float s8 = (lane < 8) ? p : 0.f;
#pragma unroll
        for (int s = 1; s < 64; s <<= 1) s8 += __shfl_xor(s8, s);

        float* ew = out;
        float* ei = out + (size_t)T_TOK * 8;
        float* ci = out + (size_t)2 * T_TOK * 8;
        float* ia = out + (size_t)3 * T_TOK * 8;
        if (lane < 8) {
            ew[(size_t)t * 8 + lane] = p / s8;
            ei[(size_t)t * 8 + lane] = (float)myidx;
            ia[(size_t)t * 8 + lane] = (float)myidx;
        } else if (lane < 16) {
            ci[(size_t)t * 8 + (lane - 8)] = (float)myidx;
        }
    }
}

extern "C" void kernel_launch(void* const* d_in, const int* in_sizes, int n_in,
                              void* d_out, int out_size, void* d_ws, size_t ws_size,
                              hipStream_t stream) {
    const float* x = (const float*)d_in[0];
    const float* w = (const float*)d_in[1];
    float* out     = (float*)d_out;

    const size_t slice      = (size_t)T_TOK * NEXP * sizeof(float);  // 4 MiB
    const size_t wfragBytes = (size_t)64 * 1024 * 16;                // 1 MiB
    const size_t extra      = wfragBytes + (size_t)T_TOK * sizeof(int) + 64;

    int ksplit = 1;
    if      (ws_size >= 4 * slice + extra) ksplit = 4;
    else if (ws_size >= 2 * slice + extra) ksplit = 2;

    float* partial = (float*)d_ws;
    u16x8* wfrag   = (u16x8*)((char*)d_ws + (size_t)ksplit * slice);
    int*   list    = (int*)((char*)wfrag + wfragBytes);
    int*   counter = list + T_TOK;

    zero_counter<<<1, 64, 0, stream>>>(counter);
    wsplit_kernel<<<128, 256, 0, stream>>>(w, wfrag);
    gate_gemm_mfma<<<ksplit * (T_TOK / 64), 256, 0, stream>>>(x, wfrag, partial, ksplit);
    gate_topk_f32<<<T_TOK / 4, 256, 0, stream>>>(partial, ksplit, out, list, counter);
    gate_repair_f64<<<256, 256, 0, stream>>>(x, w, list, counter, out);
}